// Round 3
// baseline (6271.449 us; speedup 1.0000x reference)
//
#include <hip/hip_runtime.h>
#include <cstdint>
#include <cstddef>

#define NCLS 32000
#define EMBD 512
#define HIDD 1024
#define BATCH 64
#define SEQL 256
#define NWG 256
#define K0 1536
#define K1 2048
#define K0P (K0 + 8)
#define K1P (K1 + 8)
#define BH (BATCH * HIDD)          // 65536 elements
#define HBYTES (BH * 2)            // 131072 bytes per h buffer

typedef __attribute__((ext_vector_type(8))) short short8;
typedef __attribute__((ext_vector_type(4))) float float4v;
typedef unsigned long long ull;

// ---- workspace layout (bytes) ----
// ctr[64] u32: [0]=bar, [16]=gen, [32+x]=per-XCD member count, [48+x]=per-XCD local barrier
#define WS_CTR   0
#define WS_H0G   256                         // 2 buffers bf16 [b][k]
#define WS_H1G   (WS_H0G + 2*HBYTES)
#define WS_LH    (WS_H1G + 2*HBYTES)         // 8 XCDs x (lh0 128K + lh1 128K)
#define WS_XEMB  (WS_LH + 8*2*HBYTES)        // 256*64*512*2 = 16 MB

#define SMEM_BYTES ((16*K0P + 16*K1P)*2 + (8192 + 32 + 512 + 8)*4)

__device__ __forceinline__ unsigned short f2bf(float f) {
  union { float f; uint32_t u; } x; x.f = f;
  uint32_t r = x.u + 0x7FFFu + ((x.u >> 16) & 1u);
  return (unsigned short)(r >> 16);
}

__device__ __forceinline__ float sigm(float x) {
  return 1.0f / (1.0f + __expf(-x));
}

// 4x16B loads that bypass L1 (sc0) but hit the XCD-local L2 (no sc1).
// Early-clobber outputs: loads 1-3 read address regs after load 0 writes.
__device__ __forceinline__ void ld4_sc0(const void* a0, const void* a1,
                                        const void* a2, const void* a3,
                                        short8& r0, short8& r1, short8& r2, short8& r3) {
  asm volatile(
      "global_load_dwordx4 %0, %4, off sc0\n\t"
      "global_load_dwordx4 %1, %5, off sc0\n\t"
      "global_load_dwordx4 %2, %6, off sc0\n\t"
      "global_load_dwordx4 %3, %7, off sc0\n\t"
      "s_waitcnt vmcnt(0)"
      : "=&v"(r0), "=&v"(r1), "=&v"(r2), "=&v"(r3)
      : "v"(a0), "v"(a1), "v"(a2), "v"(a3)
      : "memory");
}

// Monotonic grid barrier. Shared data crossing XCDs is sc1-only, so no
// buffer_inv / wbl2 is needed; __syncthreads drains each wave's vmcnt.
__device__ __forceinline__ void gbar(unsigned* bar, unsigned* gen, unsigned target) {
  __syncthreads();
  if (threadIdx.x == 0) {
    unsigned prev = __hip_atomic_fetch_add(bar, 1u, __ATOMIC_RELAXED, __HIP_MEMORY_SCOPE_AGENT);
    if (prev == target * NWG - 1u) {
      __hip_atomic_store(gen, target, __ATOMIC_RELAXED, __HIP_MEMORY_SCOPE_AGENT);
    } else {
      while (__hip_atomic_load(gen, __ATOMIC_RELAXED, __HIP_MEMORY_SCOPE_AGENT) < target)
        __builtin_amdgcn_s_sleep(1);
    }
  }
  __syncthreads();
}

// per-XCD monotonic barrier among nloc workgroups
__device__ __forceinline__ void lbar(unsigned* lcnt, unsigned target) {
  __syncthreads();
  if (threadIdx.x == 0) {
    __hip_atomic_fetch_add(lcnt, 1u, __ATOMIC_RELAXED, __HIP_MEMORY_SCOPE_AGENT);
    while (__hip_atomic_load(lcnt, __ATOMIC_RELAXED, __HIP_MEMORY_SCOPE_AGENT) < target)
      __builtin_amdgcn_s_sleep(1);
  }
  __syncthreads();
}

__global__ void init_bar_k(char* ws) {
  ((unsigned*)(ws + WS_CTR))[threadIdx.x] = 0u;   // 64 threads -> 64 dwords
}

// gather embeddings -> bf16 xemb[t][b][e]
__global__ void embed_k(const int* __restrict__ X, const float* __restrict__ Cemb,
                        char* __restrict__ ws) {
  uint32_t p = blockIdx.x * 256u + threadIdx.x;   // pair index, 256*64*256 = 4194304
  uint32_t t = p >> 14;
  uint32_t r = p & 16383u;
  uint32_t b = r >> 8;
  uint32_t e2 = r & 255u;
  int row = X[b * SEQL + t];
  const float2 v = *(const float2*)(Cemb + (size_t)row * EMBD + (size_t)e2 * 2);
  uint32_t lo = f2bf(v.x), hi = f2bf(v.y);
  ((uint32_t*)(ws + WS_XEMB))[p] = (hi << 16) | lo;
}

__global__ __launch_bounds__(512, 1)
void lstm_k(const float* __restrict__ Wi0, const float* __restrict__ Wc0,
            const float* __restrict__ Wf0, const float* __restrict__ Wo0,
            const float* __restrict__ Wi1, const float* __restrict__ Wc1,
            const float* __restrict__ Wf1, const float* __restrict__ Wo1,
            const float* __restrict__ bi0, const float* __restrict__ bc0,
            const float* __restrict__ bf0, const float* __restrict__ bo0,
            const float* __restrict__ bi1, const float* __restrict__ bc1,
            const float* __restrict__ bf1, const float* __restrict__ bo1,
            char* ws) {
  const int wg   = blockIdx.x;
  const int tid  = threadIdx.x;
  const int lane = tid & 63;
  const int wv   = tid >> 6;        // 0..7
  const int l15  = lane & 15;
  const int quad = lane >> 4;

  extern __shared__ char smem[];
  unsigned short* w0 = (unsigned short*)smem;        // [16][K0P] bf16
  unsigned short* w1 = w0 + 16 * K0P;                // [16][K1P] bf16
  float* red  = (float*)(w1 + 16 * K1P);             // [8 waves][64 b][16 n]
  float* bias = red + 8192;                          // [32]
  float* cst  = bias + 32;                           // [512]
  int*   meta = (int*)(cst + 512);                   // [0]=li, [1]=nloc

  unsigned short* h0g = (unsigned short*)(ws + WS_H0G);
  unsigned short* h1g = (unsigned short*)(ws + WS_H1G);
  const unsigned short* xemb = (const unsigned short*)(ws + WS_XEMB);
  unsigned* ctr = (unsigned*)(ws + WS_CTR);

  // XCD id (HW_REG_XCC_ID = hwreg 20, offset 0, width 4) [measured: learn_hip m09]
  const unsigned xcc = __builtin_amdgcn_s_getreg((3u << 11) | 20u) & 7u;
  unsigned short* lh0 = (unsigned short*)(ws + WS_LH + (size_t)xcc * 2 * HBYTES);
  unsigned short* lh1 = lh0 + BH;

  // register XCD membership
  if (tid == 0) {
    unsigned li = __hip_atomic_fetch_add(ctr + 32 + xcc, 1u,
                                         __ATOMIC_RELAXED, __HIP_MEMORY_SCOPE_AGENT);
    meta[0] = (int)li;
  }

  // zero h1g buffer 0 (read by the phase-0 pull)
  if (wg < 32) {
    ull* z = (ull*)(ws + WS_H1G);
    __hip_atomic_store(z + wg * 512 + tid, 0ull, __ATOMIC_RELAXED, __HIP_MEMORY_SCOPE_AGENT);
  }

  // ---- stage weights into LDS as bf16, layout [n = jl*4+g][k contiguous] ----
  {
    const float* W0g[4] = {Wi0, Wc0, Wf0, Wo0};
    const float* W1g[4] = {Wi1, Wc1, Wf1, Wo1};
    int jl = tid & 3;
    int kr = tid >> 2;            // 0..127
    int jg = wg * 4 + jl;
    for (int g = 0; g < 4; ++g) {
      unsigned short* dst0 = w0 + (jl * 4 + g) * K0P;
      const float* s0 = W0g[g] + jg;
      for (int k = kr; k < K0; k += 128) dst0[k] = f2bf(s0[(size_t)k * HIDD]);
      unsigned short* dst1 = w1 + (jl * 4 + g) * K1P;
      const float* s1 = W1g[g] + jg;
      for (int k = kr; k < K1; k += 128) dst1[k] = f2bf(s1[(size_t)k * HIDD]);
    }
  }
  if (tid < 32) {
    const float* B0g[4] = {bi0, bc0, bf0, bo0};
    const float* B1g[4] = {bi1, bc1, bf1, bo1};
    int lay = tid >> 4, idx = tid & 15, jl = idx >> 2, g = idx & 3;
    bias[tid] = (lay ? B1g[g] : B0g[g])[wg * 4 + jl];
  }
  cst[tid] = 0.f;

  unsigned tgt = 0;
  gbar(ctr, ctr + 16, ++tgt);   // membership counts final; h1g[0] zeroed

  if (tid == 0)
    meta[1] = (int)__hip_atomic_load(ctr + 32 + xcc, __ATOMIC_RELAXED, __HIP_MEMORY_SCOPE_AGENT);
  __syncthreads();
  const int li = meta[0], nloc = meta[1];

  // zero the XCD-local h copies (phase-0 A operand)
  ull* dl = (ull*)lh0;
  for (int c = li; c < 64; c += nloc) dl[c * 512 + tid] = 0ull;
  unsigned ltgt = (unsigned)nloc;
  lbar(ctr + 48 + xcc, ltgt);

  // phase p: waves 0-3 run L0(step p), waves 4-7 run L1(step p-1), concurrently.
  for (int p = 0; p <= SEQL; ++p) {
    const int run0 = (p < SEQL);
    const int run1 = (p >= 1);
    if (wv < 4) {
      if (run0) {
        const unsigned short* xe = xemb + (size_t)p * BATCH * EMBD;
        float4v acc0 = {0.f,0.f,0.f,0.f}, acc1 = acc0, acc2 = acc0, acc3 = acc0;
        const int kbeg = wv * 384;
        for (int i = 0; i < 12; ++i) {
          int k0 = kbeg + i * 32;
          short8 bfr = *(const short8*)(w0 + l15 * K0P + k0 + quad * 8);
          short8 f0, f1, f2, f3;
          if (k0 < HIDD) {
            const unsigned short* ab = lh0 + k0 + quad * 8 + l15 * HIDD;
            ld4_sc0(ab, ab + 16 * HIDD, ab + 32 * HIDD, ab + 48 * HIDD, f0, f1, f2, f3);
          } else {
            const unsigned short* ab = xe + (k0 - HIDD) + quad * 8 + l15 * EMBD;
            f0 = *(const short8*)(ab);
            f1 = *(const short8*)(ab + 16 * EMBD);
            f2 = *(const short8*)(ab + 32 * EMBD);
            f3 = *(const short8*)(ab + 48 * EMBD);
          }
          acc0 = __builtin_amdgcn_mfma_f32_16x16x32_bf16(f0, bfr, acc0, 0, 0, 0);
          acc1 = __builtin_amdgcn_mfma_f32_16x16x32_bf16(f1, bfr, acc1, 0, 0, 0);
          acc2 = __builtin_amdgcn_mfma_f32_16x16x32_bf16(f2, bfr, acc2, 0, 0, 0);
          acc3 = __builtin_amdgcn_mfma_f32_16x16x32_bf16(f3, bfr, acc3, 0, 0, 0);
        }
        float* rw = red + wv * 1024 + quad * 64 + l15;
        #pragma unroll
        for (int r = 0; r < 4; ++r) {
          rw[r * 16]       = acc0[r];
          rw[256 + r * 16] = acc1[r];
          rw[512 + r * 16] = acc2[r];
          rw[768 + r * 16] = acc3[r];
        }
      }
    } else {
      if (run1) {
        float4v acc0 = {0.f,0.f,0.f,0.f}, acc1 = acc0, acc2 = acc0, acc3 = acc0;
        const int kbeg = (wv - 4) * 512;
        for (int i = 0; i < 16; ++i) {
          int k0 = kbeg + i * 32;
          short8 bfr = *(const short8*)(w1 + l15 * K1P + k0 + quad * 8);
          const unsigned short* as = (k0 < HIDD) ? (lh1 + k0) : (lh0 + (k0 - HIDD));
          const unsigned short* ab = as + quad * 8 + l15 * HIDD;
          short8 f0, f1, f2, f3;
          ld4_sc0(ab, ab + 16 * HIDD, ab + 32 * HIDD, ab + 48 * HIDD, f0, f1, f2, f3);
          acc0 = __builtin_amdgcn_mfma_f32_16x16x32_bf16(f0, bfr, acc0, 0, 0, 0);
          acc1 = __builtin_amdgcn_mfma_f32_16x16x32_bf16(f1, bfr, acc1, 0, 0, 0);
          acc2 = __builtin_amdgcn_mfma_f32_16x16x32_bf16(f2, bfr, acc2, 0, 0, 0);
          acc3 = __builtin_amdgcn_mfma_f32_16x16x32_bf16(f3, bfr, acc3, 0, 0, 0);
        }
        float* rw = red + wv * 1024 + quad * 64 + l15;
        #pragma unroll
        for (int r = 0; r < 4; ++r) {
          rw[r * 16]       = acc0[r];
          rw[256 + r * 16] = acc1[r];
          rw[512 + r * 16] = acc2[r];
          rw[768 + r * 16] = acc3[r];
        }
      }
    }
    __syncthreads();
    // split epilogue: tid<256 -> L0 gates+publish, tid>=256 -> L1
    if (tid < 256) {
      if (run0) {
        int b = tid >> 2, jl = tid & 3;
        const float* rr = red + b * 16 + jl * 4;
        float4v v = *(const float4v*)rr;
        v += *(const float4v*)(rr + 1024);
        v += *(const float4v*)(rr + 2048);
        v += *(const float4v*)(rr + 3072);
        float ig = sigm(v.x + bias[jl * 4 + 0]);
        float gg = tanhf(v.y + bias[jl * 4 + 1]);
        float fg = sigm(v.z + bias[jl * 4 + 2]);
        float og = sigm(v.w + bias[jl * 4 + 3]);
        float c = fg * cst[tid] + ig * gg;
        cst[tid] = c;
        unsigned x  = f2bf(og * tanhf(c));
        unsigned x1 = (unsigned)__shfl((int)x, lane + 1);
        unsigned x2 = (unsigned)__shfl((int)x, lane + 2);
        unsigned x3 = (unsigned)__shfl((int)x, lane + 3);
        if ((lane & 3) == 0) {
          ull val = (ull)(x | (x1 << 16)) | ((ull)(x2 | (x3 << 16)) << 32);
          unsigned short* dst = h0g + (size_t)(p & 1) * BH + (size_t)b * HIDD + wg * 4;
          __hip_atomic_store((ull*)dst, val, __ATOMIC_RELAXED, __HIP_MEMORY_SCOPE_AGENT);
        }
      }
    } else {
      if (run1) {
        int t = tid - 256, b = t >> 2, jl = t & 3;
        const float* rr = red + 4096 + b * 16 + jl * 4;
        float4v v = *(const float4v*)rr;
        v += *(const float4v*)(rr + 1024);
        v += *(const float4v*)(rr + 2048);
        v += *(const float4v*)(rr + 3072);
        float ig = sigm(v.x + bias[16 + jl * 4 + 0]);
        float gg = tanhf(v.y + bias[16 + jl * 4 + 1]);
        float fg = sigm(v.z + bias[16 + jl * 4 + 2]);
        float og = sigm(v.w + bias[16 + jl * 4 + 3]);
        float c = fg * cst[tid] + ig * gg;
        cst[tid] = c;
        unsigned x  = f2bf(og * tanhf(c));
        unsigned x1 = (unsigned)__shfl((int)x, lane + 1);
        unsigned x2 = (unsigned)__shfl((int)x, lane + 2);
        unsigned x3 = (unsigned)__shfl((int)x, lane + 3);
        if ((lane & 3) == 0) {
          ull val = (ull)(x | (x1 << 16)) | ((ull)(x2 | (x3 << 16)) << 32);
          unsigned short* dst = h1g + (size_t)(p & 1) * BH + (size_t)b * HIDD + wg * 4;
          __hip_atomic_store((ull*)dst, val, __ATOMIC_RELAXED, __HIP_MEMORY_SCOPE_AGENT);
        }
      }
    }
    if (p == SEQL) break;          // final h1(255) published to h1g buf 0; done
    gbar(ctr, ctr + 16, ++tgt);    // all columns of h0(p), h1(p-1) published
    // pull fresh h into the XCD-local copy (sc1 loads -> plain stores)
    {
      const ull* s0 = (const ull*)(h0g + (size_t)(p & 1) * BH);
      const ull* s1 = (const ull*)(h1g + (size_t)(p & 1) * BH);
      for (int c = li; c < 64; c += nloc) {
        int idx = c * 512 + tid;
        ull v = (c < 32)
          ? __hip_atomic_load(s0 + idx,         __ATOMIC_RELAXED, __HIP_MEMORY_SCOPE_AGENT)
          : __hip_atomic_load(s1 + idx - 16384, __ATOMIC_RELAXED, __HIP_MEMORY_SCOPE_AGENT);
        dl[idx] = v;
      }
    }
    ltgt += (unsigned)nloc;
    lbar(ctr + 48 + xcc, ltgt);
  }
}

// logits via MFMA: out[b][n] = sum_k h1[b][k] * Wout[k][n] + bout[n]
__global__ __launch_bounds__(256, 1)
void out_gemm_k(const char* __restrict__ ws, const float* __restrict__ Wout,
                const float* __restrict__ bout, float* __restrict__ out) {
  const unsigned short* h1 = (const unsigned short*)(ws + WS_H1G);  // bf16 [64][1024], buf 0
  const int tid = threadIdx.x, lane = tid & 63, wv = tid >> 6;
  const int l15 = lane & 15, quad = lane >> 4;
  const int n0 = blockIdx.x * 128 + wv * 32;
  float4v acc[4][2];
  #pragma unroll
  for (int m = 0; m < 4; ++m)
    #pragma unroll
    for (int f = 0; f < 2; ++f) acc[m][f] = (float4v){0.f, 0.f, 0.f, 0.f};

  for (int k0 = 0; k0 < HIDD; k0 += 32) {
    short8 a[4];
    #pragma unroll
    for (int m = 0; m < 4; ++m)
      a[m] = *(const short8*)(h1 + (size_t)(l15 + 16 * m) * HIDD + k0 + quad * 8);
    short8 bf[2];
    #pragma unroll
    for (int f = 0; f < 2; ++f) {
      int n = n0 + f * 16 + l15;
      #pragma unroll
      for (int j = 0; j < 8; ++j) {
        float w = Wout[(size_t)(k0 + quad * 8 + j) * NCLS + n];
        bf[f][j] = (short)f2bf(w);
      }
    }
    #pragma unroll
    for (int m = 0; m < 4; ++m)
      #pragma unroll
      for (int f = 0; f < 2; ++f)
        acc[m][f] = __builtin_amdgcn_mfma_f32_16x16x32_bf16(a[m], bf[f], acc[m][f], 0, 0, 0);
  }
  #pragma unroll
  for (int m = 0; m < 4; ++m)
    #pragma unroll
    for (int f = 0; f < 2; ++f) {
      int n = n0 + f * 16 + l15;
      float bb = bout[n];
      #pragma unroll
      for (int r = 0; r < 4; ++r) {
        int b = m * 16 + quad * 4 + r;
        out[(size_t)b * NCLS + n] = acc[m][f][r] + bb;
      }
    }
}

extern "C" void kernel_launch(void* const* d_in, const int* in_sizes, int n_in,
                              void* d_out, int out_size, void* d_ws, size_t ws_size,
                              hipStream_t stream) {
  const int*   X    = (const int*)d_in[0];
  const float* Cemb = (const float*)d_in[1];
  const float* Wi0  = (const float*)d_in[2];
  const float* bi0  = (const float*)d_in[3];
  const float* Wc0  = (const float*)d_in[4];
  const float* bc0  = (const float*)d_in[5];
  const float* Wf0  = (const float*)d_in[6];
  const float* bf0  = (const float*)d_in[7];
  const float* Wo0  = (const float*)d_in[8];
  const float* bo0  = (const float*)d_in[9];
  const float* Wi1  = (const float*)d_in[10];
  const float* bi1  = (const float*)d_in[11];
  const float* Wc1  = (const float*)d_in[12];
  const float* bc1  = (const float*)d_in[13];
  const float* Wf1  = (const float*)d_in[14];
  const float* bf1  = (const float*)d_in[15];
  const float* Wo1  = (const float*)d_in[16];
  const float* bo1  = (const float*)d_in[17];
  const float* Wout = (const float*)d_in[18];
  const float* bout = (const float*)d_in[19];
  float* out = (float*)d_out;
  char* ws = (char*)d_ws;

  hipFuncSetAttribute((const void*)lstm_k,
                      hipFuncAttributeMaxDynamicSharedMemorySize, SMEM_BYTES);

  init_bar_k<<<1, 64, 0, stream>>>(ws);
  embed_k<<<16384, 256, 0, stream>>>(X, Cemb, ws);
  lstm_k<<<NWG, 512, SMEM_BYTES, stream>>>(Wi0, Wc0, Wf0, Wo0, Wi1, Wc1, Wf1, Wo1,
                                           bi0, bc0, bf0, bo0, bi1, bc1, bf1, bo1, ws);
  out_gemm_k<<<250, 256, 0, stream>>>(ws, Wout, bout, out);
}

// Round 4
// 4404.872 us; speedup vs baseline: 1.4238x; 1.4238x over previous
//
#include <hip/hip_runtime.h>
#include <cstdint>
#include <cstddef>

#define NCLS 32000
#define EMBD 512
#define HIDD 1024
#define BATCH 64
#define SEQL 256
#define NWG 256
#define K0 1536
#define K1 2048
#define K0P (K0 + 8)
#define K1P (K1 + 8)
#define BH (BATCH * HIDD)          // 65536 elements
#define HBYTES (BH * 2)            // 131072 bytes per h buffer

typedef __attribute__((ext_vector_type(8))) short short8;
typedef __attribute__((ext_vector_type(4))) float float4v;
typedef unsigned long long ull;

// ---- workspace layout (bytes) ----
// ctr dwords: [0]=gctr, [16]=gen, [32+x]=cnt (membership), [48]=sctr, [56]=sgen,
//             [64+16x]=xctr (per-XCD arrivals), [192+16x]=xgen (per-XCD release)
#define WS_CTR   0                           // 2048 B reserved
#define WS_H0G   2048                        // 2 buffers bf16 [b][k]
#define WS_H1G   (WS_H0G + 2*HBYTES)
#define WS_XEMB  (WS_H1G + 2*HBYTES)         // 256*64*512*2 = 16 MB

#define SMEM_BYTES ((16*K0P + 16*K1P)*2 + (8192 + 32 + 512 + 8)*4)

__device__ __forceinline__ unsigned short f2bf(float f) {
  union { float f; uint32_t u; } x; x.f = f;
  uint32_t r = x.u + 0x7FFFu + ((x.u >> 16) & 1u);
  return (unsigned short)(r >> 16);
}

__device__ __forceinline__ float sigm(float x) {
  return 1.0f / (1.0f + __expf(-x));
}

// flat monotonic barrier (startup only)
__device__ __forceinline__ void gbar(unsigned* bar, unsigned* gen, unsigned target) {
  __syncthreads();
  if (threadIdx.x == 0) {
    unsigned prev = __hip_atomic_fetch_add(bar, 1u, __ATOMIC_RELAXED, __HIP_MEMORY_SCOPE_AGENT);
    if (prev == target * NWG - 1u) {
      __hip_atomic_store(gen, target, __ATOMIC_RELAXED, __HIP_MEMORY_SCOPE_AGENT);
    } else {
      while (__hip_atomic_load(gen, __ATOMIC_RELAXED, __HIP_MEMORY_SCOPE_AGENT) < target)
        __builtin_amdgcn_s_sleep(1);
    }
  }
  __syncthreads();
}

// hierarchical monotonic barrier: per-XCD aggregation, ONE buffer_inv per XCD
// per phase (executed by the last arriver on that XCD before releasing peers).
__device__ __forceinline__ void hbar(unsigned* ctr, unsigned xcc, unsigned nloc,
                                     unsigned nxcd, unsigned tgt) {
  __syncthreads();   // drains vmcnt -> this WG's sc1 publishes are visible
  if (threadIdx.x == 0) {
    unsigned* xctr = ctr + 64 + 16 * xcc;
    unsigned* xgen = ctr + 192 + 16 * xcc;
    unsigned a = __hip_atomic_fetch_add(xctr, 1u, __ATOMIC_RELAXED, __HIP_MEMORY_SCOPE_AGENT);
    if (a == tgt * nloc - 1u) {            // last arriver on this XCD
      unsigned g = __hip_atomic_fetch_add(ctr, 1u, __ATOMIC_RELAXED, __HIP_MEMORY_SCOPE_AGENT);
      if (g == tgt * nxcd - 1u) {          // last arriver globally
        __hip_atomic_store(ctr + 16, tgt, __ATOMIC_RELAXED, __HIP_MEMORY_SCOPE_AGENT);
      } else {
        while (__hip_atomic_load(ctr + 16, __ATOMIC_RELAXED, __HIP_MEMORY_SCOPE_AGENT) < tgt) {}
      }
      asm volatile("buffer_inv sc1\n\ts_waitcnt vmcnt(0)" ::: "memory");
      __hip_atomic_store(xgen, tgt, __ATOMIC_RELAXED, __HIP_MEMORY_SCOPE_AGENT);
    } else {
      while (__hip_atomic_load(xgen, __ATOMIC_RELAXED, __HIP_MEMORY_SCOPE_AGENT) < tgt) {}
    }
  }
  __syncthreads();
}

__global__ void init_bar_k(char* ws) {
  if (threadIdx.x < 320) ((unsigned*)(ws + WS_CTR))[threadIdx.x] = 0u;
}

// gather embeddings -> bf16 xemb[t][b][e]
__global__ void embed_k(const int* __restrict__ X, const float* __restrict__ Cemb,
                        char* __restrict__ ws) {
  uint32_t p = blockIdx.x * 256u + threadIdx.x;   // pair index, 256*64*256 = 4194304
  uint32_t t = p >> 14;
  uint32_t r = p & 16383u;
  uint32_t b = r >> 8;
  uint32_t e2 = r & 255u;
  int row = X[b * SEQL + t];
  const float2 v = *(const float2*)(Cemb + (size_t)row * EMBD + (size_t)e2 * 2);
  uint32_t lo = f2bf(v.x), hi = f2bf(v.y);
  ((uint32_t*)(ws + WS_XEMB))[p] = (hi << 16) | lo;
}

__global__ __launch_bounds__(512, 1)
void lstm_k(const float* __restrict__ Wi0, const float* __restrict__ Wc0,
            const float* __restrict__ Wf0, const float* __restrict__ Wo0,
            const float* __restrict__ Wi1, const float* __restrict__ Wc1,
            const float* __restrict__ Wf1, const float* __restrict__ Wo1,
            const float* __restrict__ bi0, const float* __restrict__ bc0,
            const float* __restrict__ bf0, const float* __restrict__ bo0,
            const float* __restrict__ bi1, const float* __restrict__ bc1,
            const float* __restrict__ bf1, const float* __restrict__ bo1,
            char* ws) {
  const int wg   = blockIdx.x;
  const int tid  = threadIdx.x;
  const int lane = tid & 63;
  const int wv   = tid >> 6;        // 0..7
  const int l15  = lane & 15;
  const int quad = lane >> 4;

  extern __shared__ char smem[];
  unsigned short* w0 = (unsigned short*)smem;        // [16][K0P] bf16
  unsigned short* w1 = w0 + 16 * K0P;                // [16][K1P] bf16
  float* red  = (float*)(w1 + 16 * K1P);             // [8 waves][64 b][16 n]
  float* bias = red + 8192;                          // [32]
  float* cst  = bias + 32;                           // [512]
  int*   meta = (int*)(cst + 512);                   // [0]=nloc, [1]=nxcd

  unsigned short* h0buf = (unsigned short*)(ws + WS_H0G);
  unsigned short* h1buf = (unsigned short*)(ws + WS_H1G);
  const unsigned short* xemb = (const unsigned short*)(ws + WS_XEMB);
  unsigned* ctr = (unsigned*)(ws + WS_CTR);

  // XCD id (HW_REG_XCC_ID = hwreg 20, offset 0, width 4) [measured: learn_hip m09]
  const unsigned xcc = __builtin_amdgcn_s_getreg((3u << 11) | 20u) & 7u;

  // register XCD membership
  if (tid == 0)
    __hip_atomic_fetch_add(ctr + 32 + xcc, 1u, __ATOMIC_RELAXED, __HIP_MEMORY_SCOPE_AGENT);

  // ---- stage weights into LDS as bf16, layout [n = jl*4+g][k contiguous] ----
  {
    const float* W0g[4] = {Wi0, Wc0, Wf0, Wo0};
    const float* W1g[4] = {Wi1, Wc1, Wf1, Wo1};
    int jl = tid & 3;
    int kr = tid >> 2;            // 0..127
    int jg = wg * 4 + jl;
    for (int g = 0; g < 4; ++g) {
      unsigned short* dst0 = w0 + (jl * 4 + g) * K0P;
      const float* s0 = W0g[g] + jg;
      for (int k = kr; k < K0; k += 128) dst0[k] = f2bf(s0[(size_t)k * HIDD]);
      unsigned short* dst1 = w1 + (jl * 4 + g) * K1P;
      const float* s1 = W1g[g] + jg;
      for (int k = kr; k < K1; k += 128) dst1[k] = f2bf(s1[(size_t)k * HIDD]);
    }
  }
  if (tid < 32) {
    const float* B0g[4] = {bi0, bc0, bf0, bo0};
    const float* B1g[4] = {bi1, bc1, bf1, bo1};
    int lay = tid >> 4, idx = tid & 15, jl = idx >> 2, g = idx & 3;
    bias[tid] = (lay ? B1g[g] : B0g[g])[wg * 4 + jl];
  }
  cst[tid] = 0.f;
  if (tid < 128) {   // zero h state (buffer 0) via agent-coherent stores
    unsigned short* base = (tid < 64) ? h0buf : h1buf;
    int b = tid & 63;
    __hip_atomic_store((ull*)(base + (size_t)b * HIDD + wg * 4), 0ull,
                       __ATOMIC_RELAXED, __HIP_MEMORY_SCOPE_AGENT);
  }

  gbar(ctr + 48, ctr + 56, 1u);   // startup: membership final, h zeroed, weights staged

  if (tid == 0) {
    int nl = (int)__hip_atomic_load(ctr + 32 + xcc, __ATOMIC_RELAXED, __HIP_MEMORY_SCOPE_AGENT);
    int nx = 0;
    for (int x = 0; x < 8; ++x)
      nx += (__hip_atomic_load(ctr + 32 + x, __ATOMIC_RELAXED, __HIP_MEMORY_SCOPE_AGENT) != 0u);
    meta[0] = nl; meta[1] = nx;
  }
  __syncthreads();
  const unsigned nloc = (unsigned)meta[0], nxcd = (unsigned)meta[1];

  unsigned tgt = 0;
  // phase p: waves 0-3 run L0(step p), waves 4-7 run L1(step p-1), concurrently.
  for (int p = 0; p <= SEQL; ++p) {
    const int run0 = (p < SEQL);
    const int run1 = (p >= 1);
    if (wv < 4) {
      if (run0) {
        const unsigned short* hp = h0buf + (size_t)(p & 1) * BH;        // h0(p-1)
        const unsigned short* xe = xemb + (size_t)p * BATCH * EMBD;
        float4v acc0 = {0.f,0.f,0.f,0.f}, acc1 = acc0, acc2 = acc0, acc3 = acc0;
        const int kbeg = wv * 384;
        for (int i = 0; i < 12; ++i) {
          int k0 = kbeg + i * 32;
          short8 bfr = *(const short8*)(w0 + l15 * K0P + k0 + quad * 8);
          const unsigned short* as; int koff, stride;
          if (k0 < HIDD) { as = hp; koff = k0; stride = HIDD; }
          else           { as = xe; koff = k0 - HIDD; stride = EMBD; }
          const unsigned short* ab = as + koff + quad * 8 + (size_t)l15 * stride;
          short8 f0 = *(const short8*)(ab);
          short8 f1 = *(const short8*)(ab + 16 * stride);
          short8 f2 = *(const short8*)(ab + 32 * stride);
          short8 f3 = *(const short8*)(ab + 48 * stride);
          acc0 = __builtin_amdgcn_mfma_f32_16x16x32_bf16(f0, bfr, acc0, 0, 0, 0);
          acc1 = __builtin_amdgcn_mfma_f32_16x16x32_bf16(f1, bfr, acc1, 0, 0, 0);
          acc2 = __builtin_amdgcn_mfma_f32_16x16x32_bf16(f2, bfr, acc2, 0, 0, 0);
          acc3 = __builtin_amdgcn_mfma_f32_16x16x32_bf16(f3, bfr, acc3, 0, 0, 0);
        }
        float* rw = red + wv * 1024 + quad * 64 + l15;
        #pragma unroll
        for (int r = 0; r < 4; ++r) {
          rw[r * 16]       = acc0[r];
          rw[256 + r * 16] = acc1[r];
          rw[512 + r * 16] = acc2[r];
          rw[768 + r * 16] = acc3[r];
        }
      }
    } else {
      if (run1) {
        const unsigned short* h1p = h1buf + (size_t)((p & 1) ^ 1) * BH;  // h1(p-2)
        const unsigned short* h0c = h0buf + (size_t)(p & 1) * BH;        // h0(p-1)
        float4v acc0 = {0.f,0.f,0.f,0.f}, acc1 = acc0, acc2 = acc0, acc3 = acc0;
        const int kbeg = (wv - 4) * 512;
        for (int i = 0; i < 16; ++i) {
          int k0 = kbeg + i * 32;
          short8 bfr = *(const short8*)(w1 + l15 * K1P + k0 + quad * 8);
          const unsigned short* as; int koff;
          if (k0 < HIDD) { as = h1p; koff = k0; }
          else           { as = h0c; koff = k0 - HIDD; }
          const unsigned short* ab = as + koff + quad * 8 + (size_t)l15 * HIDD;
          short8 f0 = *(const short8*)(ab);
          short8 f1 = *(const short8*)(ab + 16 * HIDD);
          short8 f2 = *(const short8*)(ab + 32 * HIDD);
          short8 f3 = *(const short8*)(ab + 48 * HIDD);
          acc0 = __builtin_amdgcn_mfma_f32_16x16x32_bf16(f0, bfr, acc0, 0, 0, 0);
          acc1 = __builtin_amdgcn_mfma_f32_16x16x32_bf16(f1, bfr, acc1, 0, 0, 0);
          acc2 = __builtin_amdgcn_mfma_f32_16x16x32_bf16(f2, bfr, acc2, 0, 0, 0);
          acc3 = __builtin_amdgcn_mfma_f32_16x16x32_bf16(f3, bfr, acc3, 0, 0, 0);
        }
        float* rw = red + wv * 1024 + quad * 64 + l15;
        #pragma unroll
        for (int r = 0; r < 4; ++r) {
          rw[r * 16]       = acc0[r];
          rw[256 + r * 16] = acc1[r];
          rw[512 + r * 16] = acc2[r];
          rw[768 + r * 16] = acc3[r];
        }
      }
    }
    __syncthreads();
    // split epilogue: tid<256 -> L0 gates+publish, tid>=256 -> L1
    if (tid < 256) {
      if (run0) {
        int b = tid >> 2, jl = tid & 3;
        const float* rr = red + b * 16 + jl * 4;
        float4v v = *(const float4v*)rr;
        v += *(const float4v*)(rr + 1024);
        v += *(const float4v*)(rr + 2048);
        v += *(const float4v*)(rr + 3072);
        float ig = sigm(v.x + bias[jl * 4 + 0]);
        float gg = tanhf(v.y + bias[jl * 4 + 1]);
        float fg = sigm(v.z + bias[jl * 4 + 2]);
        float og = sigm(v.w + bias[jl * 4 + 3]);
        float c = fg * cst[tid] + ig * gg;
        cst[tid] = c;
        unsigned x  = f2bf(og * tanhf(c));
        unsigned x1 = (unsigned)__shfl((int)x, lane + 1);
        unsigned x2 = (unsigned)__shfl((int)x, lane + 2);
        unsigned x3 = (unsigned)__shfl((int)x, lane + 3);
        if ((lane & 3) == 0) {
          ull val = (ull)(x | (x1 << 16)) | ((ull)(x2 | (x3 << 16)) << 32);
          unsigned short* dst = h0buf + (size_t)((p & 1) ^ 1) * BH + (size_t)b * HIDD + wg * 4;
          __hip_atomic_store((ull*)dst, val, __ATOMIC_RELAXED, __HIP_MEMORY_SCOPE_AGENT);
        }
      }
    } else {
      if (run1) {
        int t = tid - 256, b = t >> 2, jl = t & 3;
        const float* rr = red + 4096 + b * 16 + jl * 4;
        float4v v = *(const float4v*)rr;
        v += *(const float4v*)(rr + 1024);
        v += *(const float4v*)(rr + 2048);
        v += *(const float4v*)(rr + 3072);
        float ig = sigm(v.x + bias[16 + jl * 4 + 0]);
        float gg = tanhf(v.y + bias[16 + jl * 4 + 1]);
        float fg = sigm(v.z + bias[16 + jl * 4 + 2]);
        float og = sigm(v.w + bias[16 + jl * 4 + 3]);
        float c = fg * cst[tid] + ig * gg;
        cst[tid] = c;
        unsigned x  = f2bf(og * tanhf(c));
        unsigned x1 = (unsigned)__shfl((int)x, lane + 1);
        unsigned x2 = (unsigned)__shfl((int)x, lane + 2);
        unsigned x3 = (unsigned)__shfl((int)x, lane + 3);
        if ((lane & 3) == 0) {
          ull val = (ull)(x | (x1 << 16)) | ((ull)(x2 | (x3 << 16)) << 32);
          unsigned short* dst = h1buf + (size_t)(p & 1) * BH + (size_t)b * HIDD + wg * 4;
          __hip_atomic_store((ull*)dst, val, __ATOMIC_RELAXED, __HIP_MEMORY_SCOPE_AGENT);
        }
      }
    }
    if (p == SEQL) break;          // final h1(255) published (buf 0); done
    hbar(ctr, xcc, nloc, nxcd, ++tgt);
  }
}

// logits via MFMA: out[b][n] = sum_k h1[b][k] * Wout[k][n] + bout[n]
__global__ __launch_bounds__(256, 1)
void out_gemm_k(const char* __restrict__ ws, const float* __restrict__ Wout,
                const float* __restrict__ bout, float* __restrict__ out) {
  const unsigned short* h1 = (const unsigned short*)(ws + WS_H1G);  // bf16 [64][1024], buf 0
  const int tid = threadIdx.x, lane = tid & 63, wv = tid >> 6;
  const int l15 = lane & 15, quad = lane >> 4;
  const int n0 = blockIdx.x * 128 + wv * 32;
  float4v acc[4][2];
  #pragma unroll
  for (int m = 0; m < 4; ++m)
    #pragma unroll
    for (int f = 0; f < 2; ++f) acc[m][f] = (float4v){0.f, 0.f, 0.f, 0.f};

  for (int k0 = 0; k0 < HIDD; k0 += 32) {
    short8 a[4];
    #pragma unroll
    for (int m = 0; m < 4; ++m)
      a[m] = *(const short8*)(h1 + (size_t)(l15 + 16 * m) * HIDD + k0 + quad * 8);
    short8 bf[2];
    #pragma unroll
    for (int f = 0; f < 2; ++f) {
      int n = n0 + f * 16 + l15;
      #pragma unroll
      for (int j = 0; j < 8; ++j) {
        float w = Wout[(size_t)(k0 + quad * 8 + j) * NCLS + n];
        bf[f][j] = (short)f2bf(w);
      }
    }
    #pragma unroll
    for (int m = 0; m < 4; ++m)
      #pragma unroll
      for (int f = 0; f < 2; ++f)
        acc[m][f] = __builtin_amdgcn_mfma_f32_16x16x32_bf16(a[m], bf[f], acc[m][f], 0, 0, 0);
  }
  #pragma unroll
  for (int m = 0; m < 4; ++m)
    #pragma unroll
    for (int f = 0; f < 2; ++f) {
      int n = n0 + f * 16 + l15;
      float bb = bout[n];
      #pragma unroll
      for (int r = 0; r < 4; ++r) {
        int b = m * 16 + quad * 4 + r;
        out[(size_t)b * NCLS + n] = acc[m][f][r] + bb;
      }
    }
}

extern "C" void kernel_launch(void* const* d_in, const int* in_sizes, int n_in,
                              void* d_out, int out_size, void* d_ws, size_t ws_size,
                              hipStream_t stream) {
  const int*   X    = (const int*)d_in[0];
  const float* Cemb = (const float*)d_in[1];
  const float* Wi0  = (const float*)d_in[2];
  const float* bi0  = (const float*)d_in[3];
  const float* Wc0  = (const float*)d_in[4];
  const float* bc0  = (const float*)d_in[5];
  const float* Wf0  = (const float*)d_in[6];
  const float* bf0  = (const float*)d_in[7];
  const float* Wo0  = (const float*)d_in[8];
  const float* bo0  = (const float*)d_in[9];
  const float* Wi1  = (const float*)d_in[10];
  const float* bi1  = (const float*)d_in[11];
  const float* Wc1  = (const float*)d_in[12];
  const float* bc1  = (const float*)d_in[13];
  const float* Wf1  = (const float*)d_in[14];
  const float* bf1  = (const float*)d_in[15];
  const float* Wo1  = (const float*)d_in[16];
  const float* bo1  = (const float*)d_in[17];
  const float* Wout = (const float*)d_in[18];
  const float* bout = (const float*)d_in[19];
  float* out = (float*)d_out;
  char* ws = (char*)d_ws;

  hipFuncSetAttribute((const void*)lstm_k,
                      hipFuncAttributeMaxDynamicSharedMemorySize, SMEM_BYTES);

  init_bar_k<<<1, 512, 0, stream>>>(ws);
  embed_k<<<16384, 256, 0, stream>>>(X, Cemb, ws);
  lstm_k<<<NWG, 512, SMEM_BYTES, stream>>>(Wi0, Wc0, Wf0, Wo0, Wi1, Wc1, Wf1, Wo1,
                                           bi0, bc0, bf0, bo0, bi1, bc1, bf1, bo1, ws);
  out_gemm_k<<<250, 256, 0, stream>>>(ws, Wout, bout, out);
}